// Round 21
// baseline (95.078 us; speedup 1.0000x reference)
//
#include <hip/hip_runtime.h>
#include <hip/hip_bf16.h>

using bf16x8 = __attribute__((ext_vector_type(8))) __bf16;
using f32x4  = __attribute__((ext_vector_type(4))) float;
using f32x16 = __attribute__((ext_vector_type(16))) float;
using i32x4  = __attribute__((ext_vector_type(4))) int;

#define MFMA_16x16x32(a, b, c) __builtin_amdgcn_mfma_f32_16x16x32_bf16((a), (b), (c), 0, 0, 0)
#define MFMA32(a, b, c)        __builtin_amdgcn_mfma_f32_32x32x16_bf16((a), (b), (c), 0, 0, 0)

#define GLOAD16(g, l)                                                         \
    __builtin_amdgcn_global_load_lds(                                         \
        (const __attribute__((address_space(1))) unsigned int*)(g),           \
        (__attribute__((address_space(3))) unsigned int*)(l), 16, 0, 0)

__device__ __forceinline__ ushort f2bf(float f) {
    return __builtin_bit_cast(ushort, (__bf16)f);
}
__device__ __forceinline__ float bf2f(ushort u) {
    union { unsigned int i; float f; } x; x.i = ((unsigned int)u) << 16; return x.f;
}
__device__ __forceinline__ unsigned pk_bf16(float lo, float hi) {
    unsigned r;
    asm volatile("v_cvt_pk_bf16_f32 %0, %1, %2" : "=v"(r) : "v"(lo), "v"(hi));
    return r;
}
__device__ __forceinline__ void pl32_swap(unsigned &a, unsigned &b) {
    asm volatile("v_permlane32_swap_b32 %0, %1" : "+v"(a), "+v"(b));
}

// unit table: tile | c0<<8 | c1<<16 (KV steps of 128), descending work.
// tiles 0-8 whole; tiles 9-15 split x2 -> 23 units, max unit = 9 steps.
#define ENC(t, a, b) ((t) | ((a) << 8) | ((b) << 16))
__device__ __constant__ unsigned UT[23] = {
    ENC(8,0,9),
    ENC(15,0,8), ENC(15,8,16), ENC(14,0,8), ENC(7,0,8),
    ENC(13,0,7), ENC(13,7,14), ENC(14,8,15), ENC(12,0,7), ENC(6,0,7),
    ENC(11,0,6), ENC(11,6,12), ENC(12,7,13), ENC(10,0,6), ENC(5,0,6),
    ENC(9,0,5),  ENC(9,5,10),  ENC(10,6,11), ENC(4,0,5),
    ENC(3,0,4),  ENC(2,0,3),   ENC(1,0,2),   ENC(0,0,1)
};

// ---------------------------------------------------------------------------
// fp32 -> bf16 vectorized convert (8 elems/thread)
// ---------------------------------------------------------------------------
__global__ __launch_bounds__(256) void cvt_bf16(
    const float* __restrict__ in, ushort* __restrict__ out, int n)
{
    const int i = (blockIdx.x * 256 + threadIdx.x) * 8;
    if (i + 8 <= n) {
        const f32x4 a = *(const f32x4*)(in + i);
        const f32x4 b = *(const f32x4*)(in + i + 4);
        union { ushort u[8]; i32x4 w; } p;
        #pragma unroll
        for (int j = 0; j < 4; ++j) { p.u[j] = f2bf(a[j]); p.u[4 + j] = f2bf(b[j]); }
        *(i32x4*)(out + i) = p.w;
    }
}

// ---------------------------------------------------------------------------
// Fused convert: x -> xbf; Wq/Wk/Wv -> wbf; optionally Wp -> wpbf.
// ---------------------------------------------------------------------------
__global__ __launch_bounds__(256) void cvt_fused(
    const float* __restrict__ x, ushort* __restrict__ xbf, int nx, int nxb,
    const float* __restrict__ w0, const float* __restrict__ w1,
    const float* __restrict__ w2, ushort* __restrict__ wbf,
    const float* __restrict__ wp, ushort* __restrict__ wpbf)
{
    const int b = (int)blockIdx.x;
    if (b < nxb) {
        const int i = (b * 256 + (int)threadIdx.x) * 8;
        if (i + 8 <= nx) {
            const f32x4 a = *(const f32x4*)(x + i);
            const f32x4 c = *(const f32x4*)(x + i + 4);
            union { ushort u[8]; i32x4 w; } p;
            #pragma unroll
            for (int j = 0; j < 4; ++j) { p.u[j] = f2bf(a[j]); p.u[4 + j] = f2bf(c[j]); }
            *(i32x4*)(xbf + i) = p.w;
        }
    } else if (b < nxb + 384) {
        const int i = ((b - nxb) * 256 + (int)threadIdx.x) * 8;
        const int w = i >> 18, off = i & 262143;
        const float* src = (w == 0) ? w0 : ((w == 1) ? w1 : w2);
        const f32x4 a = *(const f32x4*)(src + off);
        const f32x4 c = *(const f32x4*)(src + off + 4);
        union { ushort u[8]; i32x4 v; } p;
        #pragma unroll
        for (int j = 0; j < 4; ++j) { p.u[j] = f2bf(a[j]); p.u[4 + j] = f2bf(c[j]); }
        *(i32x4*)(wbf + i) = p.v;
    } else {
        const int i = ((b - nxb - 384) * 256 + (int)threadIdx.x) * 8;
        const f32x4 a = *(const f32x4*)(wp + i);
        const f32x4 c = *(const f32x4*)(wp + i + 4);
        union { ushort u[8]; i32x4 v; } p;
        #pragma unroll
        for (int j = 0; j < 4; ++j) { p.u[j] = f2bf(a[j]); p.u[4 + j] = f2bf(c[j]); }
        *(i32x4*)(wpbf + i) = p.v;
    }
}

// ---------------------------------------------------------------------------
// Fused QKV GEMM, glds staging (R13/R15-proven, 2-D grid).
// ---------------------------------------------------------------------------
__global__ __launch_bounds__(256) void gemm_qkv3(
    const ushort* __restrict__ A, const ushort* __restrict__ Wbf,
    float qscale, ushort* __restrict__ qb, ushort* __restrict__ kb,
    ushort* __restrict__ vb)
{
    __shared__ ushort lA[2][128][32];
    __shared__ ushort lB[2][128][32];
    const int wsel = blockIdx.y >> 2;
    const int n0 = (blockIdx.y & 3) * 128;
    const ushort* W = Wbf + wsel * 262144;
    ushort* out = (wsel == 0) ? qb : ((wsel == 1) ? kb : vb);
    const float scale = (wsel == 0) ? qscale : 1.0f;

    const int m0 = blockIdx.x * 128;
    const int tid  = threadIdx.x;
    const int lane = tid & 63;
    const int wave = tid >> 6;
    const int wr = (wave >> 1) * 64, wc = (wave & 1) * 64;
    const int frow = lane & 15;
    const int fkp  = (((lane >> 4) ^ ((lane >> 1) & 3))) * 8;

    const int srw  = lane >> 2;
    const int scol = ((lane & 3) ^ ((lane >> 3) & 3)) * 8;

    f32x4 acc[4][4] = {};
    auto stage = [&](int k0, int b) {
        #pragma unroll
        for (int i = 0; i < 2; ++i) {
            const int rb = (wave * 2 + i) * 16;
            GLOAD16(A + (size_t)(m0 + rb + srw) * 512 + k0 + scol, &lA[b][rb][0]);
            GLOAD16(W + (size_t)(n0 + rb + srw) * 512 + k0 + scol, &lB[b][rb][0]);
        }
    };

    stage(0, 0);
    for (int t = 0; t < 16; ++t) {
        const int p = t & 1;
        __syncthreads();
        if (t + 1 < 16) stage((t + 1) * 32, p ^ 1);

        bf16x8 af[4], bg[4];
        #pragma unroll
        for (int m = 0; m < 4; ++m) af[m] = *(const bf16x8*)&lA[p][wr + m * 16 + frow][fkp];
        #pragma unroll
        for (int n = 0; n < 4; ++n) bg[n] = *(const bf16x8*)&lB[p][wc + n * 16 + frow][fkp];
        #pragma unroll
        for (int m = 0; m < 4; ++m)
            #pragma unroll
            for (int n = 0; n < 4; ++n)
                acc[m][n] = MFMA_16x16x32(af[m], bg[n], acc[m][n]);
    }

    const int rbase = (lane >> 4) * 4;
    const int ccol  = lane & 15;
    if (wsel == 2) {
        #pragma unroll
        for (int m = 0; m < 4; ++m)
            #pragma unroll
            for (int n = 0; n < 4; ++n) {
                const int col = n0 + wc + n * 16 + ccol;
                const int row0 = m0 + wr + m * 16 + rbase;
                unsigned long long u = 0;
                #pragma unroll
                for (int r = 0; r < 4; ++r)
                    u |= ((unsigned long long)f2bf(acc[m][n][r])) << (16 * r);
                const size_t idx = ((size_t)((row0 >> 11) * 8 + (col >> 6)) * 64
                                    + (col & 63)) * 2048 + (row0 & 2047);
                *(unsigned long long*)(out + idx) = u;
            }
    } else {
        #pragma unroll
        for (int m = 0; m < 4; ++m)
            #pragma unroll
            for (int n = 0; n < 4; ++n) {
                const int col = n0 + wc + n * 16 + ccol;
                #pragma unroll
                for (int r = 0; r < 4; ++r) {
                    const int row = m0 + wr + m * 16 + rbase + r;
                    out[(((row >> 11) * 8 + (col >> 6)) * 2048 + (row & 2047)) * 64 + (col & 63)]
                        = f2bf(acc[m][n][r] * scale);
                }
            }
    }
}

// ---------------------------------------------------------------------------
// Output GEMM, glds + bf16 Wp (R14/R15-proven, 2-D grid).
// ---------------------------------------------------------------------------
__global__ __launch_bounds__(256) void gemm_out(
    const ushort* __restrict__ A, const ushort* __restrict__ W,
    const float* __restrict__ bias, float* __restrict__ out)
{
    __shared__ ushort lA[2][128][32];
    __shared__ ushort lB[2][128][32];
    const int m0 = blockIdx.x * 128;
    const int n0 = blockIdx.y * 128;
    const int tid  = threadIdx.x;
    const int lane = tid & 63;
    const int wave = tid >> 6;
    const int wr = (wave >> 1) * 64, wc = (wave & 1) * 64;
    const int frow = lane & 15;
    const int fkp  = (((lane >> 4) ^ ((lane >> 1) & 3))) * 8;

    const int srw  = lane >> 2;
    const int scol = ((lane & 3) ^ ((lane >> 3) & 3)) * 8;

    f32x4 acc[4][4] = {};
    auto stage = [&](int k0, int b) {
        #pragma unroll
        for (int i = 0; i < 2; ++i) {
            const int rb = (wave * 2 + i) * 16;
            const int row = m0 + rb + srw, c = k0 + scol;
            const size_t ia = (((size_t)(row >> 11) * 8 + (c >> 6)) * 2048
                               + (row & 2047)) * 64 + (c & 63);
            GLOAD16(A + ia, &lA[b][rb][0]);
            GLOAD16(W + (size_t)(n0 + rb + srw) * 512 + k0 + scol, &lB[b][rb][0]);
        }
    };

    stage(0, 0);
    for (int t = 0; t < 16; ++t) {
        const int p = t & 1;
        __syncthreads();
        if (t + 1 < 16) stage((t + 1) * 32, p ^ 1);

        bf16x8 af[4], bg[4];
        #pragma unroll
        for (int m = 0; m < 4; ++m) af[m] = *(const bf16x8*)&lA[p][wr + m * 16 + frow][fkp];
        #pragma unroll
        for (int n = 0; n < 4; ++n) bg[n] = *(const bf16x8*)&lB[p][wc + n * 16 + frow][fkp];
        #pragma unroll
        for (int m = 0; m < 4; ++m)
            #pragma unroll
            for (int n = 0; n < 4; ++n)
                acc[m][n] = MFMA_16x16x32(af[m], bg[n], acc[m][n]);
    }

    const int rbase = (lane >> 4) * 4;
    const int ccol  = lane & 15;
    #pragma unroll
    for (int m = 0; m < 4; ++m)
        #pragma unroll
        for (int n = 0; n < 4; ++n) {
            const int col = n0 + wc + n * 16 + ccol;
            const float bv = bias[col];
            #pragma unroll
            for (int r = 0; r < 4; ++r) {
                const int row = m0 + wr + m * 16 + rbase + r;
                out[row * 512 + col] = acc[m][n][r] + bv;
            }
        }
}

// ---------------------------------------------------------------------------
// Causal flash attention R21: R20 structure, rebalanced split table (tiles
// 9-15 split x2, 23 units/bh, max unit 9 steps). Single-buffered 32 KB K/V
// LDS, two-barrier cadence, launch_bounds(256,2) (112-116 VGPR, no spill).
// ---------------------------------------------------------------------------
__global__ __launch_bounds__(256, 2) void attn_kernel(
    const ushort* __restrict__ q, const ushort* __restrict__ k,
    const ushort* __restrict__ vt, ushort* __restrict__ att,
    ushort* __restrict__ Ob, float* __restrict__ Mb, float* __restrict__ Lb)
{
    __shared__ ushort lK[2][64][64];   // [half][s_local][d], 16 KB
    __shared__ ushort lV[2][64][64];   // [half][d][s_local], 16 KB

    const int NH   = (int)gridDim.x / 23;          // bh slices
    const int n    = (int)blockIdx.x;
    const int unit = n / NH;
    const int bh   = n % NH;
    const unsigned ue = UT[unit];
    const int tile = (int)(ue & 0xff);
    const int c0   = (int)((ue >> 8) & 0xff);
    const int c1   = (int)((ue >> 16) & 0xff);
    const int qt0  = tile * 128;

    const ushort* Q  = q  + (size_t)bh * 2048 * 64;
    const ushort* K  = k  + (size_t)bh * 2048 * 64;
    const ushort* VT = vt + (size_t)bh * 2048 * 64;
    ushort* O = att + (size_t)bh * 2048 * 64;

    const int tid = threadIdx.x;
    const int wv  = tid >> 6;
    const int l   = tid & 63;
    const int ql  = l & 31;
    const int hi  = l >> 5;
    const int wrow0 = qt0 + wv * 32;
    const int qrow  = wrow0 + ql;
    const int wmax  = wrow0 + 31;
    const int qkey  = ql & 7;
    const float LOG2E = 1.44269504088896f;

    const int srow = tid >> 2;
    const int sg   = (tid & 3) * 2;
    const int skey = srow & 7;

    bf16x8 aq[4];
    #pragma unroll
    for (int kk = 0; kk < 4; ++kk)
        aq[kk] = *(const bf16x8*)(Q + (size_t)qrow * 64 + kk * 16 + hi * 8);

    f32x16 o0 = {}, o1 = {};
    float mrun = -30000.0f, lrun = 0.0f;

    i32x4 kr[2][2], vr[2][2];
    auto loadG = [&](int s0) {
        #pragma unroll
        for (int hf = 0; hf < 2; ++hf) {
            const ushort* kp = K + (size_t)(s0 + hf * 64 + srow) * 64 + (tid & 3) * 16;
            kr[hf][0] = *(const i32x4*)(kp);
            kr[hf][1] = *(const i32x4*)(kp + 8);
            const ushort* vp = VT + (size_t)srow * 2048 + s0 + hf * 64 + (tid & 3) * 16;
            vr[hf][0] = *(const i32x4*)(vp);
            vr[hf][1] = *(const i32x4*)(vp + 8);
        }
    };
    auto writeL = [&]() {
        #pragma unroll
        for (int hf = 0; hf < 2; ++hf) {
            *(i32x4*)&lK[hf][srow][((sg    ) ^ skey) * 8] = kr[hf][0];
            *(i32x4*)&lK[hf][srow][((sg + 1) ^ skey) * 8] = kr[hf][1];
            *(i32x4*)&lV[hf][srow][((sg    ) ^ skey) * 8] = vr[hf][0];
            *(i32x4*)&lV[hf][srow][((sg + 1) ^ skey) * 8] = vr[hf][1];
        }
    };

    loadG(c0 * 128);

    for (int T = c0; T < c1; ++T) {
        const int s0 = T * 128;
        __syncthreads();                 // prior step's LDS reads done
        writeL();
        __syncthreads();                 // tile visible to all waves
        if (T + 1 < c1) loadG(s0 + 128); // next tile hides under compute

        const bool act1 = (s0 + 64 <= wmax);

        f32x16 sa0 = {}, sb0 = {}, sa1 = {}, sb1 = {};
        #pragma unroll
        for (int kk = 0; kk < 4; ++kk) {
            const bf16x8 a0 = *(const bf16x8*)&lK[0][ql]     [((2 * kk + hi) ^ qkey) * 8];
            const bf16x8 b0 = *(const bf16x8*)&lK[0][32 + ql][((2 * kk + hi) ^ qkey) * 8];
            sa0 = MFMA32(a0, aq[kk], sa0);
            sb0 = MFMA32(b0, aq[kk], sb0);
        }
        if (act1) {
            #pragma unroll
            for (int kk = 0; kk < 4; ++kk) {
                const bf16x8 a1 = *(const bf16x8*)&lK[1][ql]     [((2 * kk + hi) ^ qkey) * 8];
                const bf16x8 b1 = *(const bf16x8*)&lK[1][32 + ql][((2 * kk + hi) ^ qkey) * 8];
                sa1 = MFMA32(a1, aq[kk], sa1);
                sb1 = MFMA32(b1, aq[kk], sb1);
            }
        }

        if (s0 + 63 > wrow0) {
            #pragma unroll
            for (int rr = 0; rr < 16; ++rr) {
                const int cr = (rr & 3) + 8 * (rr >> 2) + 4 * hi;
                if (s0 + cr > qrow)      sa0[rr] = -30000.0f;
                if (s0 + 32 + cr > qrow) sb0[rr] = -30000.0f;
            }
        }
        if (act1 && (s0 + 127 > wrow0)) {
            #pragma unroll
            for (int rr = 0; rr < 16; ++rr) {
                const int cr = (rr & 3) + 8 * (rr >> 2) + 4 * hi;
                if (s0 + 64 + cr > qrow) sa1[rr] = -30000.0f;
                if (s0 + 96 + cr > qrow) sb1[rr] = -30000.0f;
            }
        }

        float tm[16];
        #pragma unroll
        for (int rr = 0; rr < 16; ++rr) tm[rr] = fmaxf(sa0[rr], sb0[rr]);
        if (act1) {
            #pragma unroll
            for (int rr = 0; rr < 16; ++rr)
                tm[rr] = fmaxf(tm[rr], fmaxf(sa1[rr], sb1[rr]));
        }
        #pragma unroll
        for (int s = 8; s > 0; s >>= 1)
            #pragma unroll
            for (int rr = 0; rr < s; ++rr) tm[rr] = fmaxf(tm[rr], tm[rr + s]);
        float pmax = fmaxf(tm[0], __shfl_xor(tm[0], 32));

        if (__any(pmax > mrun + 8.0f)) {
            const float mnew  = fmaxf(mrun, pmax);
            const float alpha = exp2f((mrun - mnew) * LOG2E);
            mrun = mnew;
            lrun *= alpha;
            #pragma unroll
            for (int rr = 0; rr < 16; ++rr) {
                const float ar = __shfl(alpha, (rr & 3) + 8 * (rr >> 2) + 4 * hi);
                o0[rr] *= ar; o1[rr] *= ar;
            }
        }

        const float mb = mrun * LOG2E;
        #pragma unroll
        for (int rr = 0; rr < 16; ++rr) {
            sa0[rr] = exp2f(fmaf(sa0[rr], LOG2E, -mb));
            sb0[rr] = exp2f(fmaf(sb0[rr], LOG2E, -mb));
        }
        if (act1) {
            #pragma unroll
            for (int rr = 0; rr < 16; ++rr) {
                sa1[rr] = exp2f(fmaf(sa1[rr], LOG2E, -mb));
                sb1[rr] = exp2f(fmaf(sb1[rr], LOG2E, -mb));
            }
        }

        float tu[16];
        #pragma unroll
        for (int rr = 0; rr < 16; ++rr) tu[rr] = sa0[rr] + sb0[rr];
        if (act1) {
            #pragma unroll
            for (int rr = 0; rr < 16; ++rr) tu[rr] += sa1[rr] + sb1[rr];
        }
        #pragma unroll
        for (int s = 8; s > 0; s >>= 1)
            #pragma unroll
            for (int rr = 0; rr < s; ++rr) tu[rr] += tu[rr + s];
        lrun += tu[0] + __shfl_xor(tu[0], 32);

        {
            unsigned paw[4][4];
            #pragma unroll
            for (int ks = 0; ks < 4; ++ks) {
                const int e = 2 * ks, f = 2 * ks + 1;
                const int ra = 4 * (e & 3), rb = 4 * (f & 3);
                unsigned A0, A1, B0, B1;
                if (e >> 2) { A0 = pk_bf16(sb0[ra], sb0[ra + 1]); A1 = pk_bf16(sb0[ra + 2], sb0[ra + 3]); }
                else        { A0 = pk_bf16(sa0[ra], sa0[ra + 1]); A1 = pk_bf16(sa0[ra + 2], sa0[ra + 3]); }
                if (f >> 2) { B0 = pk_bf16(sb0[rb], sb0[rb + 1]); B1 = pk_bf16(sb0[rb + 2], sb0[rb + 3]); }
                else        { B0 = pk_bf16(sa0[rb], sa0[rb + 1]); B1 = pk_bf16(sa0[rb + 2], sa0[rb + 3]); }
                pl32_swap(A0, B0);
                pl32_swap(A1, B1);
                paw[ks][0] = A0; paw[ks][1] = A1; paw[ks][2] = B0; paw[ks][3] = B1;
            }
            #pragma unroll
            for (int ks = 0; ks < 4; ++ks) {
                union { unsigned w[4]; bf16x8 v; } u;
                u.w[0] = paw[ks][0]; u.w[1] = paw[ks][1];
                u.w[2] = paw[ks][2]; u.w[3] = paw[ks][3];
                const bf16x8 v0 = *(const bf16x8*)&lV[0][ql]     [((2 * ks + hi) ^ qkey) * 8];
                const bf16x8 v1 = *(const bf16x8*)&lV[0][32 + ql][((2 * ks + hi) ^ qkey) * 8];
                o0 = MFMA32(u.v, v0, o0);
                o1 = MFMA32(u.v, v1, o1);
            }
        }
        if (act1) {
            unsigned paw[4][4];
            #pragma unroll
            for (int ks = 0; ks < 4; ++ks) {
                const int e = 2 * ks, f = 2 * ks + 1;
                const int ra = 4 * (e & 3), rb = 4 * (f & 3);
                unsigned A0, A1, B0, B1;
                if (e >> 2) { A0 = pk_bf16(sb1[ra], sb1[ra + 1]); A1 = pk_bf16(sb1[ra + 2], sb1[ra + 3]); }
                else        { A0 = pk_bf16(sa1[ra], sa1[ra + 1]); A1 = pk_bf16(sa1[ra + 2], sa1[ra + 3]); }
                if (f >> 2) { B0 = pk_bf16(sb1[rb], sb1[rb + 1]); B1 = pk_bf16(sb1[rb + 2], sb1[rb + 3]); }
                else        { B0 = pk_bf16(sa1[rb], sa1[rb + 1]); B1 = pk_bf16(sa1[rb + 2], sa1[rb + 3]); }
                pl32_swap(A0, B0);
                pl32_swap(A1, B1);
                paw[ks][0] = A0; paw[ks][1] = A1; paw[ks][2] = B0; paw[ks][3] = B1;
            }
            #pragma unroll
            for (int ks = 0; ks < 4; ++ks) {
                union { unsigned w[4]; bf16x8 v; } u;
                u.w[0] = paw[ks][0]; u.w[1] = paw[ks][1];
                u.w[2] = paw[ks][2]; u.w[3] = paw[ks][3];
                const bf16x8 v0 = *(const bf16x8*)&lV[1][ql]     [((2 * ks + hi) ^ qkey) * 8];
                const bf16x8 v1 = *(const bf16x8*)&lV[1][32 + ql][((2 * ks + hi) ^ qkey) * 8];
                o0 = MFMA32(u.v, v0, o0);
                o1 = MFMA32(u.v, v1, o1);
            }
        }
    }

    const float linv = 1.0f / fmaxf(lrun, 1e-30f);
    if (tile < 9) {
        #pragma unroll
        for (int rr = 0; rr < 16; ++rr) {
            const int cr = (rr & 3) + 8 * (rr >> 2) + 4 * hi;
            const float li = __shfl(linv, cr);
            const int row = wrow0 + cr;
            O[(size_t)row * 64 + ql]      = f2bf(o0[rr] * li);
            O[(size_t)row * 64 + 32 + ql] = f2bf(o1[rr] * li);
        }
    } else {
        const int pi    = bh * 7 + (tile - 9);
        const int chunk = (c0 != 0) ? 1 : 0;
        ushort* ob = Ob + (size_t)(pi * 2 + chunk) * 128 * 64 + wv * 32 * 64;
        #pragma unroll
        for (int rr = 0; rr < 16; ++rr) {
            const int cr = (rr & 3) + 8 * (rr >> 2) + 4 * hi;
            const float li = __shfl(linv, cr);
            ob[(size_t)cr * 64 + ql]      = f2bf(o0[rr] * li);
            ob[(size_t)cr * 64 + 32 + ql] = f2bf(o1[rr] * li);
        }
        if (hi == 0) {
            const int ri = (pi * 2 + chunk) * 128 + wv * 32 + ql;
            Mb[ri] = mrun;
            Lb[ri] = lrun;
        }
    }
}

// ---------------------------------------------------------------------------
// Merge split-KV partials: O = (wA*OnA + wB*OnB) / (wA+wB), w = l*exp(m-M).
// ---------------------------------------------------------------------------
__global__ __launch_bounds__(256) void merge_part(
    const ushort* __restrict__ Ob, const float* __restrict__ Mb,
    const float* __restrict__ Lb, ushort* __restrict__ att)
{
    const int pi   = (int)blockIdx.x;
    const int bh   = pi / 7;
    const int tile = 9 + pi % 7;
    const int t    = threadIdx.x;
    const int row  = t >> 1;
    const int ch   = (t & 1) * 32;
    const float LOG2E = 1.44269504088896f;

    const int riA = (pi * 2 + 0) * 128 + row;
    const int riB = (pi * 2 + 1) * 128 + row;
    const float mA = Mb[riA], lA = Lb[riA];
    const float mB = Mb[riB], lB = Lb[riB];
    const float M  = fmaxf(mA, mB);
    const float wA = lA * exp2f((mA - M) * LOG2E);
    const float wB = lB * exp2f((mB - M) * LOG2E);
    const float inv = 1.0f / fmaxf(wA + wB, 1e-30f);

    const ushort* oa = Ob + (size_t)(pi * 2 + 0) * 128 * 64 + (size_t)row * 64 + ch;
    const ushort* obp = Ob + (size_t)(pi * 2 + 1) * 128 * 64 + (size_t)row * 64 + ch;
    ushort* dst = att + (size_t)bh * 2048 * 64 + (size_t)(tile * 128 + row) * 64 + ch;
    #pragma unroll
    for (int j = 0; j < 32; ++j)
        dst[j] = f2bf((wA * bf2f(oa[j]) + wB * bf2f(obp[j])) * inv);
}

extern "C" void kernel_launch(void* const* d_in, const int* in_sizes, int n_in,
                              void* d_out, int out_size, void* d_ws, size_t ws_size,
                              hipStream_t stream) {
    const float* x  = (const float*)d_in[0];   // x_q  [4,2048,512] fp32
    const float* Wq = (const float*)d_in[1];   // [8,64,512] fp32
    const float* Wk = (const float*)d_in[2];
    const float* Wv = (const float*)d_in[3];
    const float* Wp = (const float*)d_in[4];   // [512,512] fp32
    const float* bp = (const float*)d_in[5];   // [512] fp32
    float* out = (float*)d_out;                // [4,2048,512] fp32

    const size_t NEL  = 4u * 8u * 2048u * 64u;   // 4,194,304 (all batches)
    const size_t NELB = 8u * 2048u * 64u;        // 1,048,576 (one batch)
    const size_t WPN  = 262144u;                 // Wp elements
    const float qscale = 0.04419417382415922f;   // 512^-0.5 folded into q

    if (ws_size >= 3u * NEL * sizeof(ushort)) {
        ushort* xbf = (ushort*)d_out;
        ushort* qb  = xbf + NEL;
        ushort* kb  = (ushort*)d_ws;
        ushort* vb  = kb + NEL;                  // VT [b,h,d,2048]
        ushort* ab  = vb + NEL;
        ushort* wbf = ab;                        // consumed pre-attn
        const int nxb = (int)(NEL / (256 * 8));

        // split partials in xbf (dead after gemm_qkv3): 224 pairs
        // Ob = 224*2*128*64 u16 (7.34 MB); Mb/Lb = 224*2*128 f32 each
        ushort* Ob = xbf;
        float*  Mb = (float*)(xbf + 224u * 2u * 128u * 64u);
        float*  Lb = Mb + 224u * 2u * 128u;

        const bool fuse_wp = ws_size >= (3u * NEL + WPN) * sizeof(ushort);
        ushort* wpbf = fuse_wp ? (ab + NEL) : kb;
        if (fuse_wp) {
            hipLaunchKernelGGL(cvt_fused, dim3(nxb + 384 + 128), dim3(256), 0, stream,
                               x, xbf, (int)NEL, nxb, Wq, Wk, Wv, wbf, Wp, wpbf);
        } else {
            hipLaunchKernelGGL(cvt_fused, dim3(nxb + 384), dim3(256), 0, stream,
                               x, xbf, (int)NEL, nxb, Wq, Wk, Wv, wbf, Wp, wpbf);
        }
        hipLaunchKernelGGL(gemm_qkv3, dim3(64, 12), dim3(256), 0, stream,
                           xbf, wbf, qscale, qb, kb, vb);
        hipLaunchKernelGGL(attn_kernel, dim3(23 * 32), dim3(256), 0, stream,
                           qb, kb, vb, ab, Ob, Mb, Lb);
        hipLaunchKernelGGL(merge_part, dim3(7 * 32), dim3(256), 0, stream, Ob, Mb, Lb, ab);
        if (!fuse_wp)
            hipLaunchKernelGGL(cvt_bf16, dim3(128), dim3(256), 0, stream, Wp, wpbf, (int)WPN);
        hipLaunchKernelGGL(gemm_out, dim3(64, 4), dim3(256), 0, stream, ab, wpbf, bp, out);
    } else {
        // per-batch fallback: ws need = 3 * NELB * 2 = 6.3 MB
        ushort* kb  = (ushort*)d_ws;
        ushort* vb  = kb + NELB;
        ushort* ab  = vb + NELB;
        ushort* wbf = ab;
        for (int b = 0; b < 4; ++b) {
            const float* xb = x + (size_t)b * 2048u * 512u;
            float* ob = out + (size_t)b * 2048u * 512u;
            ushort* xbf  = (ushort*)ob;
            ushort* qb   = xbf + NELB;
            ushort* wpbf = kb;
            // 56 pairs: Ob = 56*2*128*64 u16 (917504); Mb/Lb = 56*2*128 f32
            ushort* Ob = xbf;
            float*  Mb = (float*)(xbf + 56u * 2u * 128u * 64u);
            float*  Lb = Mb + 56u * 2u * 128u;
            hipLaunchKernelGGL(cvt_fused, dim3((int)(NELB / (256 * 8)) + 384), dim3(256), 0, stream,
                               xb, xbf, (int)NELB, (int)(NELB / (256 * 8)), Wq, Wk, Wv, wbf,
                               Wp, wpbf);
            hipLaunchKernelGGL(gemm_qkv3, dim3(16, 12), dim3(256), 0, stream,
                               xbf, wbf, qscale, qb, kb, vb);
            hipLaunchKernelGGL(attn_kernel, dim3(23 * 8), dim3(256), 0, stream,
                               qb, kb, vb, ab, Ob, Mb, Lb);
            hipLaunchKernelGGL(merge_part, dim3(7 * 8), dim3(256), 0, stream, Ob, Mb, Lb, ab);
            hipLaunchKernelGGL(cvt_bf16, dim3(128), dim3(256), 0, stream, Wp, wpbf, (int)WPN);
            hipLaunchKernelGGL(gemm_out, dim3(16, 4), dim3(256), 0, stream, ab, wpbf, bp, ob);
        }
    }
}

// Round 22
// 91.539 us; speedup vs baseline: 1.0387x; 1.0387x over previous
//
#include <hip/hip_runtime.h>
#include <hip/hip_bf16.h>

using bf16x8 = __attribute__((ext_vector_type(8))) __bf16;
using f32x4  = __attribute__((ext_vector_type(4))) float;
using f32x16 = __attribute__((ext_vector_type(16))) float;
using i32x4  = __attribute__((ext_vector_type(4))) int;

#define MFMA_16x16x32(a, b, c) __builtin_amdgcn_mfma_f32_16x16x32_bf16((a), (b), (c), 0, 0, 0)
#define MFMA32(a, b, c)        __builtin_amdgcn_mfma_f32_32x32x16_bf16((a), (b), (c), 0, 0, 0)

#define GLOAD16(g, l)                                                         \
    __builtin_amdgcn_global_load_lds(                                         \
        (const __attribute__((address_space(1))) unsigned int*)(g),           \
        (__attribute__((address_space(3))) unsigned int*)(l), 16, 0, 0)

__device__ __forceinline__ ushort f2bf(float f) {
    return __builtin_bit_cast(ushort, (__bf16)f);
}
__device__ __forceinline__ float bf2f(ushort u) {
    union { unsigned int i; float f; } x; x.i = ((unsigned int)u) << 16; return x.f;
}
__device__ __forceinline__ unsigned pk_bf16(float lo, float hi) {
    unsigned r;
    asm volatile("v_cvt_pk_bf16_f32 %0, %1, %2" : "=v"(r) : "v"(lo), "v"(hi));
    return r;
}
__device__ __forceinline__ void pl32_swap(unsigned &a, unsigned &b) {
    asm volatile("v_permlane32_swap_b32 %0, %1" : "+v"(a), "+v"(b));
}

// unit table: tile | c0<<8 | c1<<16  (KV steps of 128), descending work
#define ENC(t, a, b) ((t) | ((a) << 8) | ((b) << 16))
__device__ __constant__ unsigned UT[22] = {
    ENC(9,0,10), ENC(8,0,9),  ENC(15,0,8), ENC(15,8,16), ENC(14,0,8), ENC(7,0,8),
    ENC(14,8,15),ENC(13,0,7), ENC(13,7,14),ENC(12,0,7),  ENC(6,0,7),
    ENC(12,7,13),ENC(11,0,6), ENC(11,6,12),ENC(10,0,6),  ENC(5,0,6),
    ENC(10,6,11),ENC(4,0,5),  ENC(3,0,4),  ENC(2,0,3),   ENC(1,0,2),  ENC(0,0,1)
};

// ---------------------------------------------------------------------------
// fp32 -> bf16 vectorized convert (8 elems/thread)
// ---------------------------------------------------------------------------
__global__ __launch_bounds__(256) void cvt_bf16(
    const float* __restrict__ in, ushort* __restrict__ out, int n)
{
    const int i = (blockIdx.x * 256 + threadIdx.x) * 8;
    if (i + 8 <= n) {
        const f32x4 a = *(const f32x4*)(in + i);
        const f32x4 b = *(const f32x4*)(in + i + 4);
        union { ushort u[8]; i32x4 w; } p;
        #pragma unroll
        for (int j = 0; j < 4; ++j) { p.u[j] = f2bf(a[j]); p.u[4 + j] = f2bf(b[j]); }
        *(i32x4*)(out + i) = p.w;
    }
}

// ---------------------------------------------------------------------------
// Fused convert: x -> xbf; Wq/Wk/Wv -> wbf; optionally Wp -> wpbf.
// ---------------------------------------------------------------------------
__global__ __launch_bounds__(256) void cvt_fused(
    const float* __restrict__ x, ushort* __restrict__ xbf, int nx, int nxb,
    const float* __restrict__ w0, const float* __restrict__ w1,
    const float* __restrict__ w2, ushort* __restrict__ wbf,
    const float* __restrict__ wp, ushort* __restrict__ wpbf)
{
    const int b = (int)blockIdx.x;
    if (b < nxb) {
        const int i = (b * 256 + (int)threadIdx.x) * 8;
        if (i + 8 <= nx) {
            const f32x4 a = *(const f32x4*)(x + i);
            const f32x4 c = *(const f32x4*)(x + i + 4);
            union { ushort u[8]; i32x4 w; } p;
            #pragma unroll
            for (int j = 0; j < 4; ++j) { p.u[j] = f2bf(a[j]); p.u[4 + j] = f2bf(c[j]); }
            *(i32x4*)(xbf + i) = p.w;
        }
    } else if (b < nxb + 384) {
        const int i = ((b - nxb) * 256 + (int)threadIdx.x) * 8;
        const int w = i >> 18, off = i & 262143;
        const float* src = (w == 0) ? w0 : ((w == 1) ? w1 : w2);
        const f32x4 a = *(const f32x4*)(src + off);
        const f32x4 c = *(const f32x4*)(src + off + 4);
        union { ushort u[8]; i32x4 v; } p;
        #pragma unroll
        for (int j = 0; j < 4; ++j) { p.u[j] = f2bf(a[j]); p.u[4 + j] = f2bf(c[j]); }
        *(i32x4*)(wbf + i) = p.v;
    } else {
        const int i = ((b - nxb - 384) * 256 + (int)threadIdx.x) * 8;
        const f32x4 a = *(const f32x4*)(wp + i);
        const f32x4 c = *(const f32x4*)(wp + i + 4);
        union { ushort u[8]; i32x4 v; } p;
        #pragma unroll
        for (int j = 0; j < 4; ++j) { p.u[j] = f2bf(a[j]); p.u[4 + j] = f2bf(c[j]); }
        *(i32x4*)(wpbf + i) = p.v;
    }
}

// ---------------------------------------------------------------------------
// Fused QKV GEMM, glds staging (R13/R15-proven, 2-D grid).
// ---------------------------------------------------------------------------
__global__ __launch_bounds__(256) void gemm_qkv3(
    const ushort* __restrict__ A, const ushort* __restrict__ Wbf,
    float qscale, ushort* __restrict__ qb, ushort* __restrict__ kb,
    ushort* __restrict__ vb)
{
    __shared__ ushort lA[2][128][32];
    __shared__ ushort lB[2][128][32];
    const int wsel = blockIdx.y >> 2;
    const int n0 = (blockIdx.y & 3) * 128;
    const ushort* W = Wbf + wsel * 262144;
    ushort* out = (wsel == 0) ? qb : ((wsel == 1) ? kb : vb);
    const float scale = (wsel == 0) ? qscale : 1.0f;

    const int m0 = blockIdx.x * 128;
    const int tid  = threadIdx.x;
    const int lane = tid & 63;
    const int wave = tid >> 6;
    const int wr = (wave >> 1) * 64, wc = (wave & 1) * 64;
    const int frow = lane & 15;
    const int fkp  = (((lane >> 4) ^ ((lane >> 1) & 3))) * 8;

    const int srw  = lane >> 2;
    const int scol = ((lane & 3) ^ ((lane >> 3) & 3)) * 8;

    f32x4 acc[4][4] = {};
    auto stage = [&](int k0, int b) {
        #pragma unroll
        for (int i = 0; i < 2; ++i) {
            const int rb = (wave * 2 + i) * 16;
            GLOAD16(A + (size_t)(m0 + rb + srw) * 512 + k0 + scol, &lA[b][rb][0]);
            GLOAD16(W + (size_t)(n0 + rb + srw) * 512 + k0 + scol, &lB[b][rb][0]);
        }
    };

    stage(0, 0);
    for (int t = 0; t < 16; ++t) {
        const int p = t & 1;
        __syncthreads();
        if (t + 1 < 16) stage((t + 1) * 32, p ^ 1);

        bf16x8 af[4], bg[4];
        #pragma unroll
        for (int m = 0; m < 4; ++m) af[m] = *(const bf16x8*)&lA[p][wr + m * 16 + frow][fkp];
        #pragma unroll
        for (int n = 0; n < 4; ++n) bg[n] = *(const bf16x8*)&lB[p][wc + n * 16 + frow][fkp];
        #pragma unroll
        for (int m = 0; m < 4; ++m)
            #pragma unroll
            for (int n = 0; n < 4; ++n)
                acc[m][n] = MFMA_16x16x32(af[m], bg[n], acc[m][n]);
    }

    const int rbase = (lane >> 4) * 4;
    const int ccol  = lane & 15;
    if (wsel == 2) {
        #pragma unroll
        for (int m = 0; m < 4; ++m)
            #pragma unroll
            for (int n = 0; n < 4; ++n) {
                const int col = n0 + wc + n * 16 + ccol;
                const int row0 = m0 + wr + m * 16 + rbase;
                unsigned long long u = 0;
                #pragma unroll
                for (int r = 0; r < 4; ++r)
                    u |= ((unsigned long long)f2bf(acc[m][n][r])) << (16 * r);
                const size_t idx = ((size_t)((row0 >> 11) * 8 + (col >> 6)) * 64
                                    + (col & 63)) * 2048 + (row0 & 2047);
                *(unsigned long long*)(out + idx) = u;
            }
    } else {
        #pragma unroll
        for (int m = 0; m < 4; ++m)
            #pragma unroll
            for (int n = 0; n < 4; ++n) {
                const int col = n0 + wc + n * 16 + ccol;
                #pragma unroll
                for (int r = 0; r < 4; ++r) {
                    const int row = m0 + wr + m * 16 + rbase + r;
                    out[(((row >> 11) * 8 + (col >> 6)) * 2048 + (row & 2047)) * 64 + (col & 63)]
                        = f2bf(acc[m][n][r] * scale);
                }
            }
    }
}

// ---------------------------------------------------------------------------
// Output GEMM, glds + bf16 Wp (R14/R15-proven, 2-D grid).
// ---------------------------------------------------------------------------
__global__ __launch_bounds__(256) void gemm_out(
    const ushort* __restrict__ A, const ushort* __restrict__ W,
    const float* __restrict__ bias, float* __restrict__ out)
{
    __shared__ ushort lA[2][128][32];
    __shared__ ushort lB[2][128][32];
    const int m0 = blockIdx.x * 128;
    const int n0 = blockIdx.y * 128;
    const int tid  = threadIdx.x;
    const int lane = tid & 63;
    const int wave = tid >> 6;
    const int wr = (wave >> 1) * 64, wc = (wave & 1) * 64;
    const int frow = lane & 15;
    const int fkp  = (((lane >> 4) ^ ((lane >> 1) & 3))) * 8;

    const int srw  = lane >> 2;
    const int scol = ((lane & 3) ^ ((lane >> 3) & 3)) * 8;

    f32x4 acc[4][4] = {};
    auto stage = [&](int k0, int b) {
        #pragma unroll
        for (int i = 0; i < 2; ++i) {
            const int rb = (wave * 2 + i) * 16;
            const int row = m0 + rb + srw, c = k0 + scol;
            const size_t ia = (((size_t)(row >> 11) * 8 + (c >> 6)) * 2048
                               + (row & 2047)) * 64 + (c & 63);
            GLOAD16(A + ia, &lA[b][rb][0]);
            GLOAD16(W + (size_t)(n0 + rb + srw) * 512 + k0 + scol, &lB[b][rb][0]);
        }
    };

    stage(0, 0);
    for (int t = 0; t < 16; ++t) {
        const int p = t & 1;
        __syncthreads();
        if (t + 1 < 16) stage((t + 1) * 32, p ^ 1);

        bf16x8 af[4], bg[4];
        #pragma unroll
        for (int m = 0; m < 4; ++m) af[m] = *(const bf16x8*)&lA[p][wr + m * 16 + frow][fkp];
        #pragma unroll
        for (int n = 0; n < 4; ++n) bg[n] = *(const bf16x8*)&lB[p][wc + n * 16 + frow][fkp];
        #pragma unroll
        for (int m = 0; m < 4; ++m)
            #pragma unroll
            for (int n = 0; n < 4; ++n)
                acc[m][n] = MFMA_16x16x32(af[m], bg[n], acc[m][n]);
    }

    const int rbase = (lane >> 4) * 4;
    const int ccol  = lane & 15;
    #pragma unroll
    for (int m = 0; m < 4; ++m)
        #pragma unroll
        for (int n = 0; n < 4; ++n) {
            const int col = n0 + wc + n * 16 + ccol;
            const float bv = bias[col];
            #pragma unroll
            for (int r = 0; r < 4; ++r) {
                const int row = m0 + wr + m * 16 + rbase + r;
                out[row * 512 + col] = acc[m][n][r] + bv;
            }
        }
}

// ---------------------------------------------------------------------------
// Causal flash attention (R20 best config): split-KV units (22-unit table),
// single-buffered 32 KB K/V LDS, two-barrier cadence, launch_bounds(256,2).
// ---------------------------------------------------------------------------
__global__ __launch_bounds__(256, 2) void attn_kernel(
    const ushort* __restrict__ q, const ushort* __restrict__ k,
    const ushort* __restrict__ vt, ushort* __restrict__ att,
    ushort* __restrict__ Ob, float* __restrict__ Mb, float* __restrict__ Lb)
{
    __shared__ ushort lK[2][64][64];   // [half][s_local][d], 16 KB
    __shared__ ushort lV[2][64][64];   // [half][d][s_local], 16 KB

    const int NH   = (int)gridDim.x / 22;          // bh slices
    const int n    = (int)blockIdx.x;
    const int unit = n / NH;
    const int bh   = n % NH;
    const unsigned ue = UT[unit];
    const int tile = (int)(ue & 0xff);
    const int c0   = (int)((ue >> 8) & 0xff);
    const int c1   = (int)((ue >> 16) & 0xff);
    const int qt0  = tile * 128;

    const ushort* Q  = q  + (size_t)bh * 2048 * 64;
    const ushort* K  = k  + (size_t)bh * 2048 * 64;
    const ushort* VT = vt + (size_t)bh * 2048 * 64;
    ushort* O = att + (size_t)bh * 2048 * 64;

    const int tid = threadIdx.x;
    const int wv  = tid >> 6;
    const int l   = tid & 63;
    const int ql  = l & 31;
    const int hi  = l >> 5;
    const int wrow0 = qt0 + wv * 32;
    const int qrow  = wrow0 + ql;
    const int wmax  = wrow0 + 31;
    const int qkey  = ql & 7;
    const float LOG2E = 1.44269504088896f;

    const int srow = tid >> 2;
    const int sg   = (tid & 3) * 2;
    const int skey = srow & 7;

    bf16x8 aq[4];
    #pragma unroll
    for (int kk = 0; kk < 4; ++kk)
        aq[kk] = *(const bf16x8*)(Q + (size_t)qrow * 64 + kk * 16 + hi * 8);

    f32x16 o0 = {}, o1 = {};
    float mrun = -30000.0f, lrun = 0.0f;

    i32x4 kr[2][2], vr[2][2];
    auto loadG = [&](int s0) {
        #pragma unroll
        for (int hf = 0; hf < 2; ++hf) {
            const ushort* kp = K + (size_t)(s0 + hf * 64 + srow) * 64 + (tid & 3) * 16;
            kr[hf][0] = *(const i32x4*)(kp);
            kr[hf][1] = *(const i32x4*)(kp + 8);
            const ushort* vp = VT + (size_t)srow * 2048 + s0 + hf * 64 + (tid & 3) * 16;
            vr[hf][0] = *(const i32x4*)(vp);
            vr[hf][1] = *(const i32x4*)(vp + 8);
        }
    };
    auto writeL = [&]() {
        #pragma unroll
        for (int hf = 0; hf < 2; ++hf) {
            *(i32x4*)&lK[hf][srow][((sg    ) ^ skey) * 8] = kr[hf][0];
            *(i32x4*)&lK[hf][srow][((sg + 1) ^ skey) * 8] = kr[hf][1];
            *(i32x4*)&lV[hf][srow][((sg    ) ^ skey) * 8] = vr[hf][0];
            *(i32x4*)&lV[hf][srow][((sg + 1) ^ skey) * 8] = vr[hf][1];
        }
    };

    loadG(c0 * 128);

    for (int T = c0; T < c1; ++T) {
        const int s0 = T * 128;
        __syncthreads();                 // prior step's LDS reads done
        writeL();
        __syncthreads();                 // tile visible to all waves
        if (T + 1 < c1) loadG(s0 + 128); // next tile hides under compute

        const bool act1 = (s0 + 64 <= wmax);

        f32x16 sa0 = {}, sb0 = {}, sa1 = {}, sb1 = {};
        #pragma unroll
        for (int kk = 0; kk < 4; ++kk) {
            const bf16x8 a0 = *(const bf16x8*)&lK[0][ql]     [((2 * kk + hi) ^ qkey) * 8];
            const bf16x8 b0 = *(const bf16x8*)&lK[0][32 + ql][((2 * kk + hi) ^ qkey) * 8];
            sa0 = MFMA32(a0, aq[kk], sa0);
            sb0 = MFMA32(b0, aq[kk], sb0);
        }
        if (act1) {
            #pragma unroll
            for (int kk = 0; kk < 4; ++kk) {
                const bf16x8 a1 = *(const bf16x8*)&lK[1][ql]     [((2 * kk + hi) ^ qkey) * 8];
                const bf16x8 b1 = *(const bf16x8*)&lK[1][32 + ql][((2 * kk + hi) ^ qkey) * 8];
                sa1 = MFMA32(a1, aq[kk], sa1);
                sb1 = MFMA32(b1, aq[kk], sb1);
            }
        }

        if (s0 + 63 > wrow0) {
            #pragma unroll
            for (int rr = 0; rr < 16; ++rr) {
                const int cr = (rr & 3) + 8 * (rr >> 2) + 4 * hi;
                if (s0 + cr > qrow)      sa0[rr] = -30000.0f;
                if (s0 + 32 + cr > qrow) sb0[rr] = -30000.0f;
            }
        }
        if (act1 && (s0 + 127 > wrow0)) {
            #pragma unroll
            for (int rr = 0; rr < 16; ++rr) {
                const int cr = (rr & 3) + 8 * (rr >> 2) + 4 * hi;
                if (s0 + 64 + cr > qrow) sa1[rr] = -30000.0f;
                if (s0 + 96 + cr > qrow) sb1[rr] = -30000.0f;
            }
        }

        float tm[16];
        #pragma unroll
        for (int rr = 0; rr < 16; ++rr) tm[rr] = fmaxf(sa0[rr], sb0[rr]);
        if (act1) {
            #pragma unroll
            for (int rr = 0; rr < 16; ++rr)
                tm[rr] = fmaxf(tm[rr], fmaxf(sa1[rr], sb1[rr]));
        }
        #pragma unroll
        for (int s = 8; s > 0; s >>= 1)
            #pragma unroll
            for (int rr = 0; rr < s; ++rr) tm[rr] = fmaxf(tm[rr], tm[rr + s]);
        float pmax = fmaxf(tm[0], __shfl_xor(tm[0], 32));

        if (__any(pmax > mrun + 8.0f)) {
            const float mnew  = fmaxf(mrun, pmax);
            const float alpha = exp2f((mrun - mnew) * LOG2E);
            mrun = mnew;
            lrun *= alpha;
            #pragma unroll
            for (int rr = 0; rr < 16; ++rr) {
                const float ar = __shfl(alpha, (rr & 3) + 8 * (rr >> 2) + 4 * hi);
                o0[rr] *= ar; o1[rr] *= ar;
            }
        }

        const float mb = mrun * LOG2E;
        #pragma unroll
        for (int rr = 0; rr < 16; ++rr) {
            sa0[rr] = exp2f(fmaf(sa0[rr], LOG2E, -mb));
            sb0[rr] = exp2f(fmaf(sb0[rr], LOG2E, -mb));
        }
        if (act1) {
            #pragma unroll
            for (int rr = 0; rr < 16; ++rr) {
                sa1[rr] = exp2f(fmaf(sa1[rr], LOG2E, -mb));
                sb1[rr] = exp2f(fmaf(sb1[rr], LOG2E, -mb));
            }
        }

        float tu[16];
        #pragma unroll
        for (int rr = 0; rr < 16; ++rr) tu[rr] = sa0[rr] + sb0[rr];
        if (act1) {
            #pragma unroll
            for (int rr = 0; rr < 16; ++rr) tu[rr] += sa1[rr] + sb1[rr];
        }
        #pragma unroll
        for (int s = 8; s > 0; s >>= 1)
            #pragma unroll
            for (int rr = 0; rr < s; ++rr) tu[rr] += tu[rr + s];
        lrun += tu[0] + __shfl_xor(tu[0], 32);

        {
            unsigned paw[4][4];
            #pragma unroll
            for (int ks = 0; ks < 4; ++ks) {
                const int e = 2 * ks, f = 2 * ks + 1;
                const int ra = 4 * (e & 3), rb = 4 * (f & 3);
                unsigned A0, A1, B0, B1;
                if (e >> 2) { A0 = pk_bf16(sb0[ra], sb0[ra + 1]); A1 = pk_bf16(sb0[ra + 2], sb0[ra + 3]); }
                else        { A0 = pk_bf16(sa0[ra], sa0[ra + 1]); A1 = pk_bf16(sa0[ra + 2], sa0[ra + 3]); }
                if (f >> 2) { B0 = pk_bf16(sb0[rb], sb0[rb + 1]); B1 = pk_bf16(sb0[rb + 2], sb0[rb + 3]); }
                else        { B0 = pk_bf16(sa0[rb], sa0[rb + 1]); B1 = pk_bf16(sa0[rb + 2], sa0[rb + 3]); }
                pl32_swap(A0, B0);
                pl32_swap(A1, B1);
                paw[ks][0] = A0; paw[ks][1] = A1; paw[ks][2] = B0; paw[ks][3] = B1;
            }
            #pragma unroll
            for (int ks = 0; ks < 4; ++ks) {
                union { unsigned w[4]; bf16x8 v; } u;
                u.w[0] = paw[ks][0]; u.w[1] = paw[ks][1];
                u.w[2] = paw[ks][2]; u.w[3] = paw[ks][3];
                const bf16x8 v0 = *(const bf16x8*)&lV[0][ql]     [((2 * ks + hi) ^ qkey) * 8];
                const bf16x8 v1 = *(const bf16x8*)&lV[0][32 + ql][((2 * ks + hi) ^ qkey) * 8];
                o0 = MFMA32(u.v, v0, o0);
                o1 = MFMA32(u.v, v1, o1);
            }
        }
        if (act1) {
            unsigned paw[4][4];
            #pragma unroll
            for (int ks = 0; ks < 4; ++ks) {
                const int e = 2 * ks, f = 2 * ks + 1;
                const int ra = 4 * (e & 3), rb = 4 * (f & 3);
                unsigned A0, A1, B0, B1;
                if (e >> 2) { A0 = pk_bf16(sb1[ra], sb1[ra + 1]); A1 = pk_bf16(sb1[ra + 2], sb1[ra + 3]); }
                else        { A0 = pk_bf16(sa1[ra], sa1[ra + 1]); A1 = pk_bf16(sa1[ra + 2], sa1[ra + 3]); }
                if (f >> 2) { B0 = pk_bf16(sb1[rb], sb1[rb + 1]); B1 = pk_bf16(sb1[rb + 2], sb1[rb + 3]); }
                else        { B0 = pk_bf16(sa1[rb], sa1[rb + 1]); B1 = pk_bf16(sa1[rb + 2], sa1[rb + 3]); }
                pl32_swap(A0, B0);
                pl32_swap(A1, B1);
                paw[ks][0] = A0; paw[ks][1] = A1; paw[ks][2] = B0; paw[ks][3] = B1;
            }
            #pragma unroll
            for (int ks = 0; ks < 4; ++ks) {
                union { unsigned w[4]; bf16x8 v; } u;
                u.w[0] = paw[ks][0]; u.w[1] = paw[ks][1];
                u.w[2] = paw[ks][2]; u.w[3] = paw[ks][3];
                const bf16x8 v0 = *(const bf16x8*)&lV[1][ql]     [((2 * ks + hi) ^ qkey) * 8];
                const bf16x8 v1 = *(const bf16x8*)&lV[1][32 + ql][((2 * ks + hi) ^ qkey) * 8];
                o0 = MFMA32(u.v, v0, o0);
                o1 = MFMA32(u.v, v1, o1);
            }
        }
    }

    const float linv = 1.0f / fmaxf(lrun, 1e-30f);
    if (tile < 10) {
        #pragma unroll
        for (int rr = 0; rr < 16; ++rr) {
            const int cr = (rr & 3) + 8 * (rr >> 2) + 4 * hi;
            const float li = __shfl(linv, cr);
            const int row = wrow0 + cr;
            O[(size_t)row * 64 + ql]      = f2bf(o0[rr] * li);
            O[(size_t)row * 64 + 32 + ql] = f2bf(o1[rr] * li);
        }
    } else {
        const int pi    = bh * 6 + (tile - 10);
        const int chunk = (c0 != 0) ? 1 : 0;
        ushort* ob = Ob + (size_t)(pi * 2 + chunk) * 128 * 64 + wv * 32 * 64;
        #pragma unroll
        for (int rr = 0; rr < 16; ++rr) {
            const int cr = (rr & 3) + 8 * (rr >> 2) + 4 * hi;
            const float li = __shfl(linv, cr);
            ob[(size_t)cr * 64 + ql]      = f2bf(o0[rr] * li);
            ob[(size_t)cr * 64 + 32 + ql] = f2bf(o1[rr] * li);
        }
        if (hi == 0) {
            const int ri = (pi * 2 + chunk) * 128 + wv * 32 + ql;
            Mb[ri] = mrun;
            Lb[ri] = lrun;
        }
    }
}

// ---------------------------------------------------------------------------
// Merge split-KV partials: O = (wA*OnA + wB*OnB) / (wA+wB), w = l*exp(m-M).
// ---------------------------------------------------------------------------
__global__ __launch_bounds__(256) void merge_part(
    const ushort* __restrict__ Ob, const float* __restrict__ Mb,
    const float* __restrict__ Lb, ushort* __restrict__ att)
{
    const int pi   = (int)blockIdx.x;
    const int bh   = pi / 6;
    const int tile = 10 + pi % 6;
    const int t    = threadIdx.x;
    const int row  = t >> 1;
    const int ch   = (t & 1) * 32;
    const float LOG2E = 1.44269504088896f;

    const int riA = (pi * 2 + 0) * 128 + row;
    const int riB = (pi * 2 + 1) * 128 + row;
    const float mA = Mb[riA], lA = Lb[riA];
    const float mB = Mb[riB], lB = Lb[riB];
    const float M  = fmaxf(mA, mB);
    const float wA = lA * exp2f((mA - M) * LOG2E);
    const float wB = lB * exp2f((mB - M) * LOG2E);
    const float inv = 1.0f / fmaxf(wA + wB, 1e-30f);

    const ushort* oa = Ob + (size_t)(pi * 2 + 0) * 128 * 64 + (size_t)row * 64 + ch;
    const ushort* obp = Ob + (size_t)(pi * 2 + 1) * 128 * 64 + (size_t)row * 64 + ch;
    ushort* dst = att + (size_t)bh * 2048 * 64 + (size_t)(tile * 128 + row) * 64 + ch;
    #pragma unroll
    for (int j = 0; j < 32; ++j)
        dst[j] = f2bf((wA * bf2f(oa[j]) + wB * bf2f(obp[j])) * inv);
}

extern "C" void kernel_launch(void* const* d_in, const int* in_sizes, int n_in,
                              void* d_out, int out_size, void* d_ws, size_t ws_size,
                              hipStream_t stream) {
    const float* x  = (const float*)d_in[0];   // x_q  [4,2048,512] fp32
    const float* Wq = (const float*)d_in[1];   // [8,64,512] fp32
    const float* Wk = (const float*)d_in[2];
    const float* Wv = (const float*)d_in[3];
    const float* Wp = (const float*)d_in[4];   // [512,512] fp32
    const float* bp = (const float*)d_in[5];   // [512] fp32
    float* out = (float*)d_out;                // [4,2048,512] fp32

    const size_t NEL  = 4u * 8u * 2048u * 64u;   // 4,194,304 (all batches)
    const size_t NELB = 8u * 2048u * 64u;        // 1,048,576 (one batch)
    const size_t WPN  = 262144u;                 // Wp elements
    const float qscale = 0.04419417382415922f;   // 512^-0.5 folded into q

    if (ws_size >= 3u * NEL * sizeof(ushort)) {
        ushort* xbf = (ushort*)d_out;
        ushort* qb  = xbf + NEL;
        ushort* kb  = (ushort*)d_ws;
        ushort* vb  = kb + NEL;                  // VT [b,h,d,2048]
        ushort* ab  = vb + NEL;
        ushort* wbf = ab;                        // consumed pre-attn
        const int nxb = (int)(NEL / (256 * 8));

        ushort* Ob = xbf;                                        // 192*2*128*64 u16
        float*  Mb = (float*)(xbf + 192u * 2u * 128u * 64u);     // 192*2*128 f32
        float*  Lb = Mb + 192u * 2u * 128u;

        const bool fuse_wp = ws_size >= (3u * NEL + WPN) * sizeof(ushort);
        ushort* wpbf = fuse_wp ? (ab + NEL) : kb;
        if (fuse_wp) {
            hipLaunchKernelGGL(cvt_fused, dim3(nxb + 384 + 128), dim3(256), 0, stream,
                               x, xbf, (int)NEL, nxb, Wq, Wk, Wv, wbf, Wp, wpbf);
        } else {
            hipLaunchKernelGGL(cvt_fused, dim3(nxb + 384), dim3(256), 0, stream,
                               x, xbf, (int)NEL, nxb, Wq, Wk, Wv, wbf, Wp, wpbf);
        }
        hipLaunchKernelGGL(gemm_qkv3, dim3(64, 12), dim3(256), 0, stream,
                           xbf, wbf, qscale, qb, kb, vb);
        hipLaunchKernelGGL(attn_kernel, dim3(22 * 32), dim3(256), 0, stream,
                           qb, kb, vb, ab, Ob, Mb, Lb);
        hipLaunchKernelGGL(merge_part, dim3(6 * 32), dim3(256), 0, stream, Ob, Mb, Lb, ab);
        if (!fuse_wp)
            hipLaunchKernelGGL(cvt_bf16, dim3(128), dim3(256), 0, stream, Wp, wpbf, (int)WPN);
        hipLaunchKernelGGL(gemm_out, dim3(64, 4), dim3(256), 0, stream, ab, wpbf, bp, out);
    } else {
        // per-batch fallback: ws need = 3 * NELB * 2 = 6.3 MB
        ushort* kb  = (ushort*)d_ws;
        ushort* vb  = kb + NELB;
        ushort* ab  = vb + NELB;
        ushort* wbf = ab;
        for (int b = 0; b < 4; ++b) {
            const float* xb = x + (size_t)b * 2048u * 512u;
            float* ob = out + (size_t)b * 2048u * 512u;
            ushort* xbf  = (ushort*)ob;
            ushort* qb   = xbf + NELB;
            ushort* wpbf = kb;
            ushort* Ob = xbf;
            float*  Mb = (float*)(xbf + 48u * 2u * 128u * 64u);
            float*  Lb = Mb + 48u * 2u * 128u;
            hipLaunchKernelGGL(cvt_fused, dim3((int)(NELB / (256 * 8)) + 384), dim3(256), 0, stream,
                               xb, xbf, (int)NELB, (int)(NELB / (256 * 8)), Wq, Wk, Wv, wbf,
                               Wp, wpbf);
            hipLaunchKernelGGL(gemm_qkv3, dim3(16, 12), dim3(256), 0, stream,
                               xbf, wbf, qscale, qb, kb, vb);
            hipLaunchKernelGGL(attn_kernel, dim3(22 * 8), dim3(256), 0, stream,
                               qb, kb, vb, ab, Ob, Mb, Lb);
            hipLaunchKernelGGL(merge_part, dim3(6 * 8), dim3(256), 0, stream, Ob, Mb, Lb, ab);
            hipLaunchKernelGGL(cvt_bf16, dim3(128), dim3(256), 0, stream, Wp, wpbf, (int)WPN);
            hipLaunchKernelGGL(gemm_out, dim3(16, 4), dim3(256), 0, stream, ab, wpbf, bp, ob);
        }
    }
}